// Round 5
// baseline (212.625 us; speedup 1.0000x reference)
//
#include <hip/hip_runtime.h>

#define NDRUG 846
#define NPAIR 423
#define EDIM  64
#define SNB   1024
#define RLEN  100

// ---- workspace layout (floats) ----
#define G_OFF     0                          // 846*100*64 = 5,414,400
#define SCORE_OFF (G_OFF + NDRUG*RLEN*EDIM)  // 846*1024   =   866,304
#define W2_OFF    (SCORE_OFF + NDRUG*SNB)    // 846*64     =    54,144
#define B2_OFF    (W2_OFF + NDRUG*EDIM)      // 1024
#define XBUF_OFF  (B2_OFF + SNB)             // 846*64
// total = 6,390,016 floats = 25.6 MB

// ---------------------------------------------------------------------------
// K0: per drug n -- w2sum[n], g[n][100][64]; blocks n<16 also do b2sum.
// ---------------------------------------------------------------------------
__global__ __launch_bounds__(256, 4) void k0_prep(
    const float* __restrict__ W1, const float* __restrict__ W2,
    const float* __restrict__ b2, const float* __restrict__ drug_table,
    const float* __restrict__ rela_table,
    float* __restrict__ g_ws, float* __restrict__ w2_ws,
    float* __restrict__ b2sum_ws)
{
  __shared__ __align__(16) float drT[8192];   // [e][128]: r-chunks of 32/wave, XOR-swizzled
  __shared__ float demb_s[EDIM];

  int n  = blockIdx.x;
  int t  = threadIdx.x;
  int w4 = __builtin_amdgcn_readfirstlane(t >> 6);
  int ln = t & 63;

  // w2sum[n][e] = sum_f W2[n][e][f]  (no LDS dependency)
  {
    int e = t >> 2, q = t & 3;
    const float4* w2p4 = reinterpret_cast<const float4*>(W2 + (size_t)n*4096);
    float4 a = w2p4[e*16 + q*4 + 0], b = w2p4[e*16 + q*4 + 1];
    float4 c = w2p4[e*16 + q*4 + 2], d = w2p4[e*16 + q*4 + 3];
    float s16 = (a.x+a.y+a.z+a.w) + (b.x+b.y+b.z+b.w)
              + (c.x+c.y+c.z+c.w) + (d.x+d.y+d.z+d.w);
    s16 += __shfl_xor(s16, 1);
    s16 += __shfl_xor(s16, 2);
    if (q == 0) w2_ws[n*EDIM + e] = s16;
  }
  // b2sum fold: blocks 0..15 each cover 64 s
  if (n < 16) {
    int sl = t >> 2, q = t & 3;
    int s = n*64 + sl;
    const float4* p = reinterpret_cast<const float4*>(b2 + (size_t)s*EDIM) + q*4;
    float4 a = p[0], b = p[1], c = p[2], d = p[3];
    float v = (a.x+a.y+a.z+a.w) + (b.x+b.y+b.z+b.w)
            + (c.x+c.y+c.z+c.w) + (d.x+d.y+d.z+d.w);
    v += __shfl_xor(v, 1);
    v += __shfl_xor(v, 2);
    if (q == 0) b2sum_ws[s] = v;
  }
  if (t < EDIM) demb_s[t] = drug_table[(size_t)n*EDIM + t];
  __syncthreads();

  // stage drT[e][swz(pos)] = rela[r][e] * demb[e];  pos = (r/25)*32 + r%25
  {
    const float4* rel4 = reinterpret_cast<const float4*>(rela_table);
    for (int i4 = t; i4 < 1600; i4 += 256) {
      float4 rv = rel4[i4];
      int r  = i4 >> 4;
      int e0 = (i4 & 15) << 2;
      int w  = (r*41) >> 10;        // r/25 for r<100
      int pos = w*32 + (r - w*25);
      float vals[4] = {rv.x, rv.y, rv.z, rv.w};
      #pragma unroll
      for (int k = 0; k < 4; ++k) {
        int e = e0 + k;
        drT[e*128 + (pos ^ ((e & 7) << 2))] = vals[k] * demb_s[e];
      }
    }
  }
  __syncthreads();

  // g[n][r][f=ln] = sum_e drT[e][r] * W1[n][e][f];  wave w4 owns r = w4*25..+24
  {
    float acc[25];
    #pragma unroll
    for (int i = 0; i < 25; ++i) acc[i] = 0.f;
    const float* w1p = W1 + (size_t)n*4096 + ln;
    #pragma unroll 4
    for (int e = 0; e < 64; ++e) {
      float w1v = w1p[e*64];
      const float* br = drT + e*128 + (w4 << 5);
      int swz = (e & 7) << 2;
      #pragma unroll
      for (int q = 0; q < 6; ++q) {
        float4 d4 = *reinterpret_cast<const float4*>(br + ((q*4) ^ swz));
        acc[q*4+0] = fmaf(d4.x, w1v, acc[q*4+0]);
        acc[q*4+1] = fmaf(d4.y, w1v, acc[q*4+1]);
        acc[q*4+2] = fmaf(d4.z, w1v, acc[q*4+2]);
        acc[q*4+3] = fmaf(d4.w, w1v, acc[q*4+3]);
      }
      float4 d6 = *reinterpret_cast<const float4*>(br + (24 ^ swz));
      acc[24] = fmaf(d6.x, w1v, acc[24]);
    }
    float* gp = g_ws + (size_t)n*6400 + (size_t)(w4*25)*64 + ln;
    #pragma unroll
    for (int rr = 0; rr < 25; ++rr) gp[rr*64] = acc[rr];
  }
}

// ---------------------------------------------------------------------------
// K1: block (pair p, half h) -- scores for drugs {2p,2p+1}, s in [h*512,+512).
// b1 loaded once per s, shared by both drugs (halves b1 cache traffic).
// grid = 848 (h*424 + p): both halves of a pair land on the same XCD.
// ---------------------------------------------------------------------------
__global__ __launch_bounds__(256, 4) void k1_score(
    const int*   __restrict__ adj_relation, const float* __restrict__ b1,
    const float* __restrict__ g_ws,  const float* __restrict__ w2_ws,
    const float* __restrict__ b2sum_ws, float* __restrict__ score_ws)
{
  __shared__ __align__(16) float g2[2*RLEN*65];   // 52,000 B
  int bid = blockIdx.x;
  int h = (bid >= 424) ? 1 : 0;
  int p = bid - h*424;
  if (p >= NPAIR) return;                 // uniform across block, before barriers
  int n0 = p*2;
  int t = threadIdx.x, ln = t & 63;
  int fq = ln & 3, sh = t >> 2;

  // stage g for both drugs (row pad 65 to spread banks by rel)
  {
    const float4* src = reinterpret_cast<const float4*>(g_ws + (size_t)n0*6400);
    for (int i4 = t; i4 < 3200; i4 += 256) {
      float4 v = src[i4];
      int row = i4 >> 4, e0 = (i4 & 15) << 2;
      float* dst = g2 + row*65 + e0;
      dst[0] = v.x; dst[1] = v.y; dst[2] = v.z; dst[3] = v.w;
    }
  }
  float w2r[2][16];
  #pragma unroll
  for (int d = 0; d < 2; ++d) {
    const float4* wp = reinterpret_cast<const float4*>(w2_ws + (size_t)(n0+d)*EDIM);
    #pragma unroll
    for (int jj = 0; jj < 4; ++jj) {
      float4 v4 = wp[jj*4 + fq];
      w2r[d][jj*4+0] = v4.x; w2r[d][jj*4+1] = v4.y;
      w2r[d][jj*4+2] = v4.z; w2r[d][jj*4+3] = v4.w;
    }
  }
  __syncthreads();

  #pragma unroll 2
  for (int it = 0; it < 8; ++it) {
    int s = h*512 + it*64 + sh;
    const float4* b1r = reinterpret_cast<const float4*>(b1 + (size_t)s*EDIM);
    float4 bv[4];
    #pragma unroll
    for (int jj = 0; jj < 4; ++jj) bv[jj] = b1r[jj*4 + fq];
    float b2v  = b2sum_ws[s];
    int   rel0 = adj_relation[(size_t)n0*SNB + s];
    int   rel1 = adj_relation[(size_t)(n0+1)*SNB + s];
    #pragma unroll
    for (int d = 0; d < 2; ++d) {
      int rel = d ? rel1 : rel0;
      const float* gp = g2 + (size_t)(d*RLEN + rel)*65;
      float a2 = 0.f;
      #pragma unroll
      for (int jj = 0; jj < 4; ++jj) {
        float2 ga = *reinterpret_cast<const float2*>(gp + jj*16 + fq*4);
        float2 gb = *reinterpret_cast<const float2*>(gp + jj*16 + fq*4 + 2);
        a2 = fmaf(fmaxf(ga.x + bv[jj].x, 0.f), w2r[d][jj*4+0], a2);
        a2 = fmaf(fmaxf(ga.y + bv[jj].y, 0.f), w2r[d][jj*4+1], a2);
        a2 = fmaf(fmaxf(gb.x + bv[jj].z, 0.f), w2r[d][jj*4+2], a2);
        a2 = fmaf(fmaxf(gb.y + bv[jj].w, 0.f), w2r[d][jj*4+3], a2);
      }
      a2 += __shfl_xor(a2, 1);
      a2 += __shfl_xor(a2, 2);
      if (fq == 0) score_ws[(size_t)(n0+d)*SNB + s] = a2 + b2v;
    }
  }
}

// ---------------------------------------------------------------------------
// K2: per drug -- softmax over 1024, sparse ent gather, linear+relu -> xbuf
// ---------------------------------------------------------------------------
__global__ __launch_bounds__(256, 4) void k2_final(
    const int*   __restrict__ adj_tail, const float* __restrict__ drug_table,
    const float* __restrict__ ent_table, const float* __restrict__ lin_W,
    const float* __restrict__ lin_b, const float* __restrict__ score_ws,
    float* __restrict__ xbuf)
{
  __shared__ float red_s[256];
  __shared__ float went_s[EDIM];
  __shared__ float demb_s[EDIM];
  __shared__ float mred[8];

  int n  = blockIdx.x;
  int t  = threadIdx.x;
  int w4 = __builtin_amdgcn_readfirstlane(t >> 6);
  int ln = t & 63;

  if (t < EDIM) demb_s[t] = drug_table[(size_t)n*EDIM + t];

  float av[4];
  {
    float sc[4];
    #pragma unroll
    for (int p = 0; p < 4; ++p) sc[p] = score_ws[(size_t)n*SNB + p*256 + t];
    float m = fmaxf(fmaxf(sc[0], sc[1]), fmaxf(sc[2], sc[3]));
    #pragma unroll
    for (int o = 32; o >= 1; o >>= 1) m = fmaxf(m, __shfl_xor(m, o));
    if (ln == 0) mred[w4] = m;
    __syncthreads();
    float M = fmaxf(fmaxf(mred[0], mred[1]), fmaxf(mred[2], mred[3]));
    float sum = 0.f;
    #pragma unroll
    for (int p = 0; p < 4; ++p) { av[p] = __expf(sc[p] - M); sum += av[p]; }
    #pragma unroll
    for (int o = 32; o >= 1; o >>= 1) sum += __shfl_xor(sum, o);
    if (ln == 0) mred[4 + w4] = sum;
    __syncthreads();
    float S = (mred[4] + mred[5]) + (mred[6] + mred[7]);
    float inv = 1.0f / S;
    #pragma unroll
    for (int p = 0; p < 4; ++p) av[p] *= inv;
  }

  // sparse gather: each wave handles its own 4 chunks (typically 1-2 active total)
  {
    float acc4 = 0.f;
    const int* tails = adj_tail + (size_t)n*SNB;
    #pragma unroll
    for (int p = 0; p < 4; ++p) {
      unsigned long long mm = __ballot(av[p] > 2e-9f);
      int sbase = p*256 + w4*64;
      while (mm) {
        int b = __ffsll(mm) - 1; mm &= mm - 1;
        float a = __shfl(av[p], b);
        acc4 = fmaf(a, ent_table[(size_t)tails[sbase + b]*EDIM + ln], acc4);
      }
    }
    red_s[w4*64 + ln] = acc4;
  }
  __syncthreads();
  if (t < EDIM)
    went_s[t] = (red_s[t] + red_s[64 + t]) + (red_s[128 + t] + red_s[192 + t]);
  __syncthreads();

  // x = relu([went, demb] @ lin_W^T + lin_b)
  {
    float acc = 0.f;
    const float* lw = lin_W + (size_t)ln*128 + w4*32;
    #pragma unroll
    for (int k = 0; k < 32; ++k) {
      int kk = w4*32 + k;
      float cv = (kk < 64) ? went_s[kk] : demb_s[kk - 64];
      acc = fmaf(cv, lw[k], acc);
    }
    red_s[w4*64 + ln] = acc;
  }
  __syncthreads();
  if (t < EDIM) {
    float x = lin_b[t] + (red_s[t] + red_s[64 + t]) + (red_s[128 + t] + red_s[192 + t]);
    xbuf[(size_t)n*EDIM + t] = fmaxf(x, 0.f);
  }
}

// ---------------------------------------------------------------------------
// bn: one block per channel e — stats + apply fused
// ---------------------------------------------------------------------------
__global__ __launch_bounds__(256) void bn_kernel(
    const float* __restrict__ xbuf, const float* __restrict__ gamma,
    const float* __restrict__ beta, float* __restrict__ out)
{
  __shared__ float r1[4], r2[4];
  int e = blockIdx.x, t = threadIdx.x;
  float v[4];
  float s = 0.f, s2 = 0.f;
  #pragma unroll
  for (int k = 0; k < 4; ++k) {
    int nn = t + k*256;
    v[k] = (nn < NDRUG) ? xbuf[(size_t)nn*EDIM + e] : 0.f;
    s += v[k]; s2 += v[k]*v[k];
  }
  #pragma unroll
  for (int o = 32; o >= 1; o >>= 1) { s += __shfl_xor(s, o); s2 += __shfl_xor(s2, o); }
  if ((t & 63) == 0) { r1[t >> 6] = s; r2[t >> 6] = s2; }
  __syncthreads();
  float S  = r1[0] + r1[1] + r1[2] + r1[3];
  float S2 = r2[0] + r2[1] + r2[2] + r2[3];
  float mean = S / (float)NDRUG;
  float var  = S2 / (float)NDRUG - mean*mean;
  float sc   = gamma[e] * rsqrtf(var + 1e-5f);
  float sh   = beta[e] - mean*sc;
  #pragma unroll
  for (int k = 0; k < 4; ++k) {
    int nn = t + k*256;
    if (nn < NDRUG) out[(size_t)nn*EDIM + e] = v[k]*sc + sh;
  }
}

// ---------------------------------------------------------------------------
extern "C" void kernel_launch(void* const* d_in, const int* in_sizes, int n_in,
                              void* d_out, int out_size, void* d_ws, size_t ws_size,
                              hipStream_t stream)
{
  const int*   adj_tail   = (const int*)d_in[1];
  const int*   adj_rel    = (const int*)d_in[2];
  const float* drug_table = (const float*)d_in[3];
  const float* rela_table = (const float*)d_in[4];
  const float* ent_table  = (const float*)d_in[5];
  const float* W1         = (const float*)d_in[6];
  const float* b1         = (const float*)d_in[7];
  const float* W2         = (const float*)d_in[8];
  const float* b2         = (const float*)d_in[9];
  const float* lin_W      = (const float*)d_in[10];
  const float* lin_b      = (const float*)d_in[11];
  const float* gamma      = (const float*)d_in[12];
  const float* beta       = (const float*)d_in[13];

  float* ws       = (float*)d_ws;
  float* g_ws     = ws + G_OFF;
  float* score_ws = ws + SCORE_OFF;
  float* w2_ws    = ws + W2_OFF;
  float* b2sum_ws = ws + B2_OFF;
  float* xbuf     = ws + XBUF_OFF;
  float* out      = (float*)d_out;

  hipLaunchKernelGGL(k0_prep, dim3(NDRUG), dim3(256), 0, stream,
                     W1, W2, b2, drug_table, rela_table, g_ws, w2_ws, b2sum_ws);
  hipLaunchKernelGGL(k1_score, dim3(848), dim3(256), 0, stream,
                     adj_rel, b1, g_ws, w2_ws, b2sum_ws, score_ws);
  hipLaunchKernelGGL(k2_final, dim3(NDRUG), dim3(256), 0, stream,
                     adj_tail, drug_table, ent_table, lin_W, lin_b, score_ws, xbuf);
  hipLaunchKernelGGL(bn_kernel, dim3(EDIM), dim3(256), 0, stream,
                     xbuf, gamma, beta, out);
}

// Round 7
// 171.558 us; speedup vs baseline: 1.2394x; 1.2394x over previous
//
#include <hip/hip_runtime.h>

#define NDRUG 846
#define EDIM  64
#define SNB   1024
#define RLEN  100

// ---- workspace layout (floats); total ~3.9 MB ----
#define SCORE_OFF 0                          // 846*1024 = 866304
#define W2_OFF    (SCORE_OFF + NDRUG*SNB)    // 846*64   =  54144
#define B2_OFF    (W2_OFF + NDRUG*EDIM)      // 1024
#define XBUF_OFF  (B2_OFF + SNB)             // 846*64

// ---------------------------------------------------------------------------
// P0: row sums, fully coalesced streaming.
// rows 0..54143  : w2_ws[n*64+e] = sum_f W2[n][e][f]   (row = n*64+e)
// rows 54144..55167: b2sum_ws[s] = sum_f b2[s][f]
// grid = 55168/64 = 862 blocks x 256 thr (4 lanes per row).
// ---------------------------------------------------------------------------
__global__ __launch_bounds__(256) void p0_rows(
    const float* __restrict__ W2, const float* __restrict__ b2,
    float* __restrict__ w2_ws, float* __restrict__ b2sum_ws)
{
  int t = threadIdx.x;
  int row = blockIdx.x*64 + (t >> 2);
  int q = t & 3;
  const float* src = (row < NDRUG*EDIM)
      ? W2 + (size_t)row*64
      : b2 + (size_t)(row - NDRUG*EDIM)*64;
  const float4* p = reinterpret_cast<const float4*>(src) + q*4;
  float4 a = p[0], b = p[1], c = p[2], d = p[3];
  float v = (a.x+a.y+a.z+a.w) + (b.x+b.y+b.z+b.w)
          + (c.x+c.y+c.z+c.w) + (d.x+d.y+d.z+d.w);
  v += __shfl_xor(v, 1);
  v += __shfl_xor(v, 2);
  if (q == 0) {
    if (row < NDRUG*EDIM) w2_ws[row] = v;
    else                  b2sum_ws[row - NDRUG*EDIM] = v;
  }
}

// ---------------------------------------------------------------------------
// K1: block (n, h) -- g for drug n (redundant per half; W1 L2/L3-hot for the
// pair since 848%8==0 keeps both halves on one XCD), then scores for 512 s.
// LDS 25.6 KB -> ~6 blocks/CU. g stored XOR-swizzled (float4 idx ^ (r&15)).
// ---------------------------------------------------------------------------
__global__ __launch_bounds__(256, 4) void k1_score(
    const int*   __restrict__ adj_relation,
    const float* __restrict__ drug_table, const float* __restrict__ rela_table,
    const float* __restrict__ W1, const float* __restrict__ b1,
    const float* __restrict__ w2_ws, const float* __restrict__ b2sum_ws,
    float* __restrict__ score_ws)
{
  __shared__ __align__(16) float g_s[RLEN*64];   // swizzled rows, 25.6 KB

  int bid = blockIdx.x;
  int h = (bid >= 848) ? 1 : 0;
  int n = bid - h*848;
  if (n >= NDRUG) return;                        // whole-block uniform exit

  int t  = threadIdx.x;
  int w4 = __builtin_amdgcn_readfirstlane(t >> 6);
  int ln = t & 63;
  int fq = ln & 3, sh = t >> 2;
  int s0 = h*512;

  // ---- phase 1: g[r][f=ln] = sum_e (demb[e]*rela[r][e]) * W1[n][e][f] ------
  // wave w4 owns r = w4*25 .. +24; demb folded into w1c; rela via uniform loads
  {
    const float* w1p   = W1 + (size_t)n*4096 + ln;
    const float* dembg = drug_table + (size_t)n*EDIM;
    int rbase = w4*25;
    float acc[25];
    {
      float w1c[32];
      #pragma unroll
      for (int e = 0; e < 32; ++e) w1c[e] = w1p[e*64] * dembg[e];
      #pragma unroll
      for (int rr = 0; rr < 25; ++rr) {
        const float* rp = rela_table + (size_t)(rbase + rr)*EDIM;
        float a = 0.f;
        #pragma unroll
        for (int e = 0; e < 32; ++e) a = fmaf(rp[e], w1c[e], a);
        acc[rr] = a;
      }
    }
    {
      float w1c[32];
      #pragma unroll
      for (int e = 0; e < 32; ++e) w1c[e] = w1p[(e+32)*64] * dembg[e+32];
      #pragma unroll
      for (int rr = 0; rr < 25; ++rr) {
        const float* rp = rela_table + (size_t)(rbase + rr)*EDIM + 32;
        float a = acc[rr];
        #pragma unroll
        for (int e = 0; e < 32; ++e) a = fmaf(rp[e], w1c[e], a);
        int r = rbase + rr;
        // element (r, ln) -> float idx r*64 + ((ln>>2)^(r&15))*4 + (ln&3)
        g_s[r*64 + (((ln >> 2) ^ (r & 15)) << 2) + (ln & 3)] = a;
      }
    }
  }

  // ---- prefetch phase-2 operands BEFORE the barrier (hides their latency) --
  float w2r[16];
  {
    const float4* wp = reinterpret_cast<const float4*>(w2_ws + (size_t)n*EDIM);
    #pragma unroll
    for (int jj = 0; jj < 4; ++jj) {
      float4 v4 = wp[jj*4 + fq];
      w2r[jj*4+0] = v4.x; w2r[jj*4+1] = v4.y;
      w2r[jj*4+2] = v4.z; w2r[jj*4+3] = v4.w;
    }
  }
  int relv[8]; float b2v[8];
  #pragma unroll
  for (int it = 0; it < 8; ++it) {
    int s = s0 + it*64 + sh;
    relv[it] = adj_relation[(size_t)n*SNB + s];
    b2v[it]  = b2sum_ws[s];
  }
  __syncthreads();

  // ---- phase 2: score[s] = sum_f relu(g[rel][f]+b1[s][f])*w2sum[f]+b2sum[s]
  // 4 lanes per s; f block j = jj*4+fq read at swizzled float4 idx j^(rel&15).
  #pragma unroll 2
  for (int it = 0; it < 8; ++it) {
    int s   = s0 + it*64 + sh;
    int rel = relv[it];
    int m   = rel & 15;
    const float4* b1r   = reinterpret_cast<const float4*>(b1 + (size_t)s*EDIM);
    const float*  gbase = g_s + rel*64;
    float a2 = 0.f;
    #pragma unroll
    for (int jj = 0; jj < 4; ++jj) {
      float4 bv = b1r[jj*4 + fq];
      float4 gv = *reinterpret_cast<const float4*>(gbase + (((jj*4 + fq) ^ m) << 2));
      a2 = fmaf(fmaxf(gv.x + bv.x, 0.f), w2r[jj*4+0], a2);
      a2 = fmaf(fmaxf(gv.y + bv.y, 0.f), w2r[jj*4+1], a2);
      a2 = fmaf(fmaxf(gv.z + bv.z, 0.f), w2r[jj*4+2], a2);
      a2 = fmaf(fmaxf(gv.w + bv.w, 0.f), w2r[jj*4+3], a2);
    }
    a2 += __shfl_xor(a2, 1);
    a2 += __shfl_xor(a2, 2);
    if (fq == 0) score_ws[(size_t)n*SNB + s] = a2 + b2v[it];
  }
}

// ---------------------------------------------------------------------------
// K2: per drug -- softmax over 1024, sparse ent gather, linear+relu -> xbuf
// ---------------------------------------------------------------------------
__global__ __launch_bounds__(256, 4) void k2_final(
    const int*   __restrict__ adj_tail, const float* __restrict__ drug_table,
    const float* __restrict__ ent_table, const float* __restrict__ lin_W,
    const float* __restrict__ lin_b, const float* __restrict__ score_ws,
    float* __restrict__ xbuf)
{
  __shared__ float red_s[256];
  __shared__ float went_s[EDIM];
  __shared__ float demb_s[EDIM];
  __shared__ float mred[8];

  int n  = blockIdx.x;
  int t  = threadIdx.x;
  int w4 = __builtin_amdgcn_readfirstlane(t >> 6);
  int ln = t & 63;

  if (t < EDIM) demb_s[t] = drug_table[(size_t)n*EDIM + t];

  float av[4];
  {
    float sc[4];
    #pragma unroll
    for (int p = 0; p < 4; ++p) sc[p] = score_ws[(size_t)n*SNB + p*256 + t];
    float m = fmaxf(fmaxf(sc[0], sc[1]), fmaxf(sc[2], sc[3]));
    #pragma unroll
    for (int o = 32; o >= 1; o >>= 1) m = fmaxf(m, __shfl_xor(m, o));
    if (ln == 0) mred[w4] = m;
    __syncthreads();
    float M = fmaxf(fmaxf(mred[0], mred[1]), fmaxf(mred[2], mred[3]));
    float sum = 0.f;
    #pragma unroll
    for (int p = 0; p < 4; ++p) { av[p] = __expf(sc[p] - M); sum += av[p]; }
    #pragma unroll
    for (int o = 32; o >= 1; o >>= 1) sum += __shfl_xor(sum, o);
    if (ln == 0) mred[4 + w4] = sum;
    __syncthreads();
    float S = (mred[4] + mred[5]) + (mred[6] + mred[7]);
    float inv = 1.0f / S;
    #pragma unroll
    for (int p = 0; p < 4; ++p) av[p] *= inv;
  }

  // sparse gather (softmax is near-one-hot: ~1 active neighbor per drug)
  {
    float acc4 = 0.f;
    const int* tails = adj_tail + (size_t)n*SNB;
    #pragma unroll
    for (int p = 0; p < 4; ++p) {
      unsigned long long mm = __ballot(av[p] > 2e-9f);
      int sbase = p*256 + w4*64;
      while (mm) {
        int b = __ffsll(mm) - 1; mm &= mm - 1;
        float a = __shfl(av[p], b);
        acc4 = fmaf(a, ent_table[(size_t)tails[sbase + b]*EDIM + ln], acc4);
      }
    }
    red_s[w4*64 + ln] = acc4;
  }
  __syncthreads();
  if (t < EDIM)
    went_s[t] = (red_s[t] + red_s[64 + t]) + (red_s[128 + t] + red_s[192 + t]);
  __syncthreads();

  // x = relu([went, demb] @ lin_W^T + lin_b)
  {
    float acc = 0.f;
    const float* lw = lin_W + (size_t)ln*128 + w4*32;
    #pragma unroll
    for (int k = 0; k < 32; ++k) {
      int kk = w4*32 + k;
      float cv = (kk < 64) ? went_s[kk] : demb_s[kk - 64];
      acc = fmaf(cv, lw[k], acc);
    }
    red_s[w4*64 + ln] = acc;
  }
  __syncthreads();
  if (t < EDIM) {
    float x = lin_b[t] + (red_s[t] + red_s[64 + t]) + (red_s[128 + t] + red_s[192 + t]);
    xbuf[(size_t)n*EDIM + t] = fmaxf(x, 0.f);
  }
}

// ---------------------------------------------------------------------------
// bn: one block per channel e — stats + apply fused
// ---------------------------------------------------------------------------
__global__ __launch_bounds__(256) void bn_kernel(
    const float* __restrict__ xbuf, const float* __restrict__ gamma,
    const float* __restrict__ beta, float* __restrict__ out)
{
  __shared__ float r1[4], r2[4];
  int e = blockIdx.x, t = threadIdx.x;
  float v[4];
  float s = 0.f, s2 = 0.f;
  #pragma unroll
  for (int k = 0; k < 4; ++k) {
    int nn = t + k*256;
    v[k] = (nn < NDRUG) ? xbuf[(size_t)nn*EDIM + e] : 0.f;
    s += v[k]; s2 += v[k]*v[k];
  }
  #pragma unroll
  for (int o = 32; o >= 1; o >>= 1) { s += __shfl_xor(s, o); s2 += __shfl_xor(s2, o); }
  if ((t & 63) == 0) { r1[t >> 6] = s; r2[t >> 6] = s2; }
  __syncthreads();
  float S  = r1[0] + r1[1] + r1[2] + r1[3];
  float S2 = r2[0] + r2[1] + r2[2] + r2[3];
  float mean = S / (float)NDRUG;
  float var  = S2 / (float)NDRUG - mean*mean;
  float sc   = gamma[e] * rsqrtf(var + 1e-5f);
  float sh   = beta[e] - mean*sc;
  #pragma unroll
  for (int k = 0; k < 4; ++k) {
    int nn = t + k*256;
    if (nn < NDRUG) out[(size_t)nn*EDIM + e] = v[k]*sc + sh;
  }
}

// ---------------------------------------------------------------------------
extern "C" void kernel_launch(void* const* d_in, const int* in_sizes, int n_in,
                              void* d_out, int out_size, void* d_ws, size_t ws_size,
                              hipStream_t stream)
{
  const int*   adj_tail   = (const int*)d_in[1];
  const int*   adj_rel    = (const int*)d_in[2];
  const float* drug_table = (const float*)d_in[3];
  const float* rela_table = (const float*)d_in[4];
  const float* ent_table  = (const float*)d_in[5];
  const float* W1         = (const float*)d_in[6];
  const float* b1         = (const float*)d_in[7];
  const float* W2         = (const float*)d_in[8];
  const float* b2         = (const float*)d_in[9];
  const float* lin_W      = (const float*)d_in[10];
  const float* lin_b      = (const float*)d_in[11];
  const float* gamma      = (const float*)d_in[12];
  const float* beta       = (const float*)d_in[13];

  float* ws       = (float*)d_ws;
  float* score_ws = ws + SCORE_OFF;
  float* w2_ws    = ws + W2_OFF;
  float* b2sum_ws = ws + B2_OFF;
  float* xbuf     = ws + XBUF_OFF;
  float* out      = (float*)d_out;

  hipLaunchKernelGGL(p0_rows, dim3(862), dim3(256), 0, stream,
                     W2, b2, w2_ws, b2sum_ws);
  hipLaunchKernelGGL(k1_score, dim3(1696), dim3(256), 0, stream,
                     adj_rel, drug_table, rela_table, W1, b1,
                     w2_ws, b2sum_ws, score_ws);
  hipLaunchKernelGGL(k2_final, dim3(NDRUG), dim3(256), 0, stream,
                     adj_tail, drug_table, ent_table, lin_W, lin_b,
                     score_ws, xbuf);
  hipLaunchKernelGGL(bn_kernel, dim3(EDIM), dim3(256), 0, stream,
                     xbuf, gamma, beta, out);
}

// Round 9
// 150.855 us; speedup vs baseline: 1.4095x; 1.1372x over previous
//
#include <hip/hip_runtime.h>

#define NDRUG 846
#define EDIM  64
#define SNB   1024
#define RLEN  100

// ---- workspace layout (floats) ----
#define W2_OFF   0                        // 846*64 = 54144
#define B2_OFF   (W2_OFF + NDRUG*EDIM)    // 1024
#define XBUF_OFF (B2_OFF + SNB)           // 846*64

// ---------------------------------------------------------------------------
// P0: row sums, fully coalesced streaming.
// rows 0..54143   : w2_ws[n*64+e] = sum_f W2[n][e][f]
// rows 54144..55167: b2sum_ws[s]  = sum_f b2[s][f]
// ---------------------------------------------------------------------------
__global__ __launch_bounds__(256) void p0_rows(
    const float* __restrict__ W2, const float* __restrict__ b2,
    float* __restrict__ w2_ws, float* __restrict__ b2sum_ws)
{
  int t = threadIdx.x;
  int row = blockIdx.x*64 + (t >> 2);
  int q = t & 3;
  const float* src = (row < NDRUG*EDIM)
      ? W2 + (size_t)row*64
      : b2 + (size_t)(row - NDRUG*EDIM)*64;
  const float4* p = reinterpret_cast<const float4*>(src) + q*4;
  float4 a = p[0], b = p[1], c = p[2], d = p[3];
  float v = (a.x+a.y+a.z+a.w) + (b.x+b.y+b.z+b.w)
          + (c.x+c.y+c.z+c.w) + (d.x+d.y+d.z+d.w);
  v += __shfl_xor(v, 1);
  v += __shfl_xor(v, 2);
  if (q == 0) {
    if (row < NDRUG*EDIM) w2_ws[row] = v;
    else                  b2sum_ws[row - NDRUG*EDIM] = v;
  }
}

// ---------------------------------------------------------------------------
// gnn_main: one block (256 thr, 4 waves) per drug. Full fusion.
// Phase 1 is e-outer: per e one coalesced W1 column load (lane=f) and 25
// UNIFORM broadcast LDS reads of dr[e][r] -> 25 independent FMAs into acc[25].
// No big register arrays -> no rematerialization / no spill.
// LDS 39.3 KB -> 4 blocks/CU -> 1024 slots >= 846 (no tail).
// ---------------------------------------------------------------------------
__global__ __launch_bounds__(256, 4) void gnn_main(
    const int*   __restrict__ adj_tail,  const int* __restrict__ adj_relation,
    const float* __restrict__ drug_table, const float* __restrict__ rela_table,
    const float* __restrict__ ent_table, const float* __restrict__ W1,
    const float* __restrict__ b1,        const float* __restrict__ lin_W,
    const float* __restrict__ lin_b,     const float* __restrict__ w2_ws,
    const float* __restrict__ b2sum_ws,  float* __restrict__ xbuf)
{
  __shared__ __align__(16) float lds[10048];
  float* g_s     = lds;           // 6400: [100][64], XOR-swizzled rows
  float* dr_s    = lds + 6400;    // 3584: [32][112]; wave w slot = w*28 + rr
  float* score_s = dr_s;          // 1024  (alias: dr dead after phase 1)
  float* red_s   = dr_s + 1024;   // 256
  float* went_s  = dr_s + 1280;   // 64
  float* mred    = dr_s + 1344;   // 8
  float* demb_s  = lds + 9984;    // 64

  int n  = blockIdx.x;
  int t  = threadIdx.x;
  int w4 = __builtin_amdgcn_readfirstlane(t >> 6);   // wave 0..3 (uniform)
  int ln = t & 63;
  int fq = ln & 3, sh = t >> 2;

  if (t < EDIM) demb_s[t] = drug_table[(size_t)n*EDIM + t];

  // prefetch w2sum fragment (global, no LDS dependency)
  float w2r[16];
  {
    const float4* wp = reinterpret_cast<const float4*>(w2_ws + (size_t)n*EDIM);
    #pragma unroll
    for (int jj = 0; jj < 4; ++jj) {
      float4 v4 = wp[jj*4 + fq];
      w2r[jj*4+0] = v4.x; w2r[jj*4+1] = v4.y;
      w2r[jj*4+2] = v4.z; w2r[jj*4+3] = v4.w;
    }
  }
  __syncthreads();

  // ---- phase 1: g[r][f=ln] = sum_e (demb[e]*rela[r][e]) * W1[n][e][f] ------
  float acc[25];
  #pragma unroll
  for (int i = 0; i < 25; ++i) acc[i] = 0.f;

  const float*  w1p  = W1 + (size_t)n*4096 + ln;
  const float4* rel4 = reinterpret_cast<const float4*>(rela_table);

  #pragma unroll
  for (int Hh = 0; Hh < 2; ++Hh) {
    // stage dr_s[e_loc][slot(r)] = rela[r][Hh*32+e_loc] * demb[Hh*32+e_loc]
    for (int i4 = t; i4 < 800; i4 += 256) {
      int r  = i4 >> 3;
      int eq = i4 & 7;
      float4 rv = rel4[r*16 + Hh*8 + eq];
      int w   = (r*41) >> 10;            // r/25 for r<100
      int pos = w*28 + (r - w*25);
      int e0  = eq*4;
      float* dst = dr_s + pos;
      dst[(e0+0)*112] = rv.x * demb_s[Hh*32 + e0+0];
      dst[(e0+1)*112] = rv.y * demb_s[Hh*32 + e0+1];
      dst[(e0+2)*112] = rv.z * demb_s[Hh*32 + e0+2];
      dst[(e0+3)*112] = rv.w * demb_s[Hh*32 + e0+3];
    }
    __syncthreads();

    const float* w1h = w1p + Hh*2048;
    #pragma unroll 2
    for (int e = 0; e < 32; ++e) {
      float w1v = w1h[e*64];                       // coalesced 64-lane load
      const float* dre = dr_s + e*112 + w4*28;     // wave-uniform base
      float4 d0 = *reinterpret_cast<const float4*>(dre);
      float4 d1 = *reinterpret_cast<const float4*>(dre + 4);
      float4 d2 = *reinterpret_cast<const float4*>(dre + 8);
      float4 d3 = *reinterpret_cast<const float4*>(dre + 12);
      float4 d4 = *reinterpret_cast<const float4*>(dre + 16);
      float4 d5 = *reinterpret_cast<const float4*>(dre + 20);
      float  dl = dre[24];
      acc[ 0] = fmaf(d0.x, w1v, acc[ 0]);
      acc[ 1] = fmaf(d0.y, w1v, acc[ 1]);
      acc[ 2] = fmaf(d0.z, w1v, acc[ 2]);
      acc[ 3] = fmaf(d0.w, w1v, acc[ 3]);
      acc[ 4] = fmaf(d1.x, w1v, acc[ 4]);
      acc[ 5] = fmaf(d1.y, w1v, acc[ 5]);
      acc[ 6] = fmaf(d1.z, w1v, acc[ 6]);
      acc[ 7] = fmaf(d1.w, w1v, acc[ 7]);
      acc[ 8] = fmaf(d2.x, w1v, acc[ 8]);
      acc[ 9] = fmaf(d2.y, w1v, acc[ 9]);
      acc[10] = fmaf(d2.z, w1v, acc[10]);
      acc[11] = fmaf(d2.w, w1v, acc[11]);
      acc[12] = fmaf(d3.x, w1v, acc[12]);
      acc[13] = fmaf(d3.y, w1v, acc[13]);
      acc[14] = fmaf(d3.z, w1v, acc[14]);
      acc[15] = fmaf(d3.w, w1v, acc[15]);
      acc[16] = fmaf(d4.x, w1v, acc[16]);
      acc[17] = fmaf(d4.y, w1v, acc[17]);
      acc[18] = fmaf(d4.z, w1v, acc[18]);
      acc[19] = fmaf(d4.w, w1v, acc[19]);
      acc[20] = fmaf(d5.x, w1v, acc[20]);
      acc[21] = fmaf(d5.y, w1v, acc[21]);
      acc[22] = fmaf(d5.z, w1v, acc[22]);
      acc[23] = fmaf(d5.w, w1v, acc[23]);
      acc[24] = fmaf(dl,   w1v, acc[24]);
    }
    __syncthreads();   // Hh=0: before re-stage; Hh=1: before score_s writes
  }

  // write g swizzled: element (r, ln) -> r*64 + ((ln>>2)^(r&15))*4 + (ln&3)
  {
    int rbase = w4*25;
    #pragma unroll
    for (int rr = 0; rr < 25; ++rr) {
      int r = rbase + rr;
      g_s[r*64 + (((ln >> 2) ^ (r & 15)) << 2) + (ln & 3)] = acc[rr];
    }
  }
  __syncthreads();

  // ---- phase 2: score[s] = sum_f relu(g[rel][f]+b1[s][f])*w2sum[f]+b2sum[s]
  // 4 lanes per s; 64 s per iteration, 16 iterations.
  #pragma unroll 2
  for (int it = 0; it < 16; ++it) {
    int s   = it*64 + sh;
    int rel = adj_relation[(size_t)n*SNB + s];
    float b2v = b2sum_ws[s];
    int m   = rel & 15;
    const float4* b1r   = reinterpret_cast<const float4*>(b1 + (size_t)s*EDIM);
    const float*  gbase = g_s + rel*64;
    float a2 = 0.f;
    #pragma unroll
    for (int jj = 0; jj < 4; ++jj) {
      float4 bv = b1r[jj*4 + fq];
      float4 gv = *reinterpret_cast<const float4*>(gbase + (((jj*4 + fq) ^ m) << 2));
      a2 = fmaf(fmaxf(gv.x + bv.x, 0.f), w2r[jj*4+0], a2);
      a2 = fmaf(fmaxf(gv.y + bv.y, 0.f), w2r[jj*4+1], a2);
      a2 = fmaf(fmaxf(gv.z + bv.z, 0.f), w2r[jj*4+2], a2);
      a2 = fmaf(fmaxf(gv.w + bv.w, 0.f), w2r[jj*4+3], a2);
    }
    a2 += __shfl_xor(a2, 1);
    a2 += __shfl_xor(a2, 2);
    if (fq == 0) score_s[s] = a2 + b2v;
  }
  __syncthreads();

  // ---- phase 3: softmax over 1024 (4 scores/thread) ------------------------
  float av[4];
  {
    float sc[4];
    #pragma unroll
    for (int p = 0; p < 4; ++p) sc[p] = score_s[p*256 + t];
    float mm = fmaxf(fmaxf(sc[0], sc[1]), fmaxf(sc[2], sc[3]));
    #pragma unroll
    for (int o = 32; o >= 1; o >>= 1) mm = fmaxf(mm, __shfl_xor(mm, o));
    if (ln == 0) mred[w4] = mm;
    __syncthreads();
    float M = fmaxf(fmaxf(mred[0], mred[1]), fmaxf(mred[2], mred[3]));
    float sum = 0.f;
    #pragma unroll
    for (int p = 0; p < 4; ++p) { av[p] = __expf(sc[p] - M); sum += av[p]; }
    #pragma unroll
    for (int o = 32; o >= 1; o >>= 1) sum += __shfl_xor(sum, o);
    if (ln == 0) mred[4 + w4] = sum;
    __syncthreads();
    float S = (mred[4] + mred[5]) + (mred[6] + mred[7]);
    float inv = 1.0f / S;
    #pragma unroll
    for (int p = 0; p < 4; ++p) av[p] *= inv;
  }

  // ---- phase 4: weighted_ent via per-wave ballot gather --------------------
  {
    float acc4 = 0.f;
    const int* tails = adj_tail + (size_t)n*SNB;
    #pragma unroll
    for (int p = 0; p < 4; ++p) {
      unsigned long long mk = __ballot(av[p] > 2e-9f);
      int sbase = p*256 + w4*64;
      while (mk) {
        int b = __ffsll(mk) - 1; mk &= mk - 1;     // wave-uniform loop
        float a = __shfl(av[p], b);
        acc4 = fmaf(a, ent_table[(size_t)tails[sbase + b]*EDIM + ln], acc4);
      }
    }
    red_s[w4*64 + ln] = acc4;
  }
  __syncthreads();
  if (t < EDIM)
    went_s[t] = (red_s[t] + red_s[64 + t]) + (red_s[128 + t] + red_s[192 + t]);
  __syncthreads();

  // ---- phase 5: x = relu([went, demb] @ lin_W^T + lin_b) -------------------
  {
    float acc5 = 0.f;
    const float* lw = lin_W + (size_t)ln*128 + w4*32;
    #pragma unroll
    for (int k = 0; k < 32; ++k) {
      int kk = w4*32 + k;
      float cv = (kk < 64) ? went_s[kk] : demb_s[kk - 64];
      acc5 = fmaf(cv, lw[k], acc5);
    }
    red_s[w4*64 + ln] = acc5;
  }
  __syncthreads();
  if (t < EDIM) {
    float x = lin_b[t] + (red_s[t] + red_s[64 + t]) + (red_s[128 + t] + red_s[192 + t]);
    xbuf[(size_t)n*EDIM + t] = fmaxf(x, 0.f);
  }
}

// ---------------------------------------------------------------------------
// bn: one block per channel e — stats + apply fused
// ---------------------------------------------------------------------------
__global__ __launch_bounds__(256) void bn_kernel(
    const float* __restrict__ xbuf, const float* __restrict__ gamma,
    const float* __restrict__ beta, float* __restrict__ out)
{
  __shared__ float r1[4], r2[4];
  int e = blockIdx.x, t = threadIdx.x;
  float v[4];
  float s = 0.f, s2 = 0.f;
  #pragma unroll
  for (int k = 0; k < 4; ++k) {
    int nn = t + k*256;
    v[k] = (nn < NDRUG) ? xbuf[(size_t)nn*EDIM + e] : 0.f;
    s += v[k]; s2 += v[k]*v[k];
  }
  #pragma unroll
  for (int o = 32; o >= 1; o >>= 1) { s += __shfl_xor(s, o); s2 += __shfl_xor(s2, o); }
  if ((t & 63) == 0) { r1[t >> 6] = s; r2[t >> 6] = s2; }
  __syncthreads();
  float S  = r1[0] + r1[1] + r1[2] + r1[3];
  float S2 = r2[0] + r2[1] + r2[2] + r2[3];
  float mean = S / (float)NDRUG;
  float var  = S2 / (float)NDRUG - mean*mean;
  float sc   = gamma[e] * rsqrtf(var + 1e-5f);
  float sh   = beta[e] - mean*sc;
  #pragma unroll
  for (int k = 0; k < 4; ++k) {
    int nn = t + k*256;
    if (nn < NDRUG) out[(size_t)nn*EDIM + e] = v[k]*sc + sh;
  }
}

// ---------------------------------------------------------------------------
extern "C" void kernel_launch(void* const* d_in, const int* in_sizes, int n_in,
                              void* d_out, int out_size, void* d_ws, size_t ws_size,
                              hipStream_t stream)
{
  const int*   adj_tail   = (const int*)d_in[1];
  const int*   adj_rel    = (const int*)d_in[2];
  const float* drug_table = (const float*)d_in[3];
  const float* rela_table = (const float*)d_in[4];
  const float* ent_table  = (const float*)d_in[5];
  const float* W1         = (const float*)d_in[6];
  const float* b1         = (const float*)d_in[7];
  const float* W2         = (const float*)d_in[8];
  const float* b2         = (const float*)d_in[9];
  const float* lin_W      = (const float*)d_in[10];
  const float* lin_b      = (const float*)d_in[11];
  const float* gamma      = (const float*)d_in[12];
  const float* beta       = (const float*)d_in[13];

  float* ws       = (float*)d_ws;
  float* w2_ws    = ws + W2_OFF;
  float* b2sum_ws = ws + B2_OFF;
  float* xbuf     = ws + XBUF_OFF;
  float* out      = (float*)d_out;

  hipLaunchKernelGGL(p0_rows, dim3(862), dim3(256), 0, stream,
                     W2, b2, w2_ws, b2sum_ws);
  hipLaunchKernelGGL(gnn_main, dim3(NDRUG), dim3(256), 0, stream,
                     adj_tail, adj_rel, drug_table, rela_table, ent_table,
                     W1, b1, lin_W, lin_b, w2_ws, b2sum_ws, xbuf);
  hipLaunchKernelGGL(bn_kernel, dim3(EDIM), dim3(256), 0, stream,
                     xbuf, gamma, beta, out);
}